// Round 3
// baseline (1630.882 us; speedup 1.0000x reference)
//
#include <hip/hip_runtime.h>
#include <math.h>

#define B_ 16
#define D_ 256
#define M_ 2048
#define N_ 2048
#define EPSF 1e-8f
#define AVAL (1.0f/2048.0f)   // a_i = 1/M = b_j = 1/N ; m = 1
#define NCH 32                // row-chunks (blocks) per batch in sinkhorn_kernel

typedef __bf16  bf16x8 __attribute__((ext_vector_type(8)));
typedef float   f32x4  __attribute__((ext_vector_type(4)));

__device__ __forceinline__ float wredsum(float x){
  #pragma unroll
  for (int off=32; off; off>>=1) x += __shfl_xor(x, off);
  return x;
}
__device__ __forceinline__ float wredmax(float x){
  #pragma unroll
  for (int off=32; off; off>>=1) x = fmaxf(x, __shfl_xor(x, off));
  return x;
}
__device__ __forceinline__ unsigned short f2bf(float x){
  unsigned int v = __float_as_uint(x);
  unsigned int r = (v + 0x7fffu + ((v>>16)&1u)) >> 16;   // RNE
  return (unsigned short)r;
}
__device__ __forceinline__ float bf2f(unsigned short u){ return __uint_as_float(((unsigned int)u)<<16); }
__device__ __forceinline__ float h2f(unsigned short h){
  _Float16 x; __builtin_memcpy(&x,&h,2); return (float)x;
}
__device__ __forceinline__ unsigned short f2h(float x){
  _Float16 h = (_Float16)x; unsigned short u; __builtin_memcpy(&u,&h,2); return u;
}

// async global->LDS, 16B per lane.
__device__ __forceinline__ void gll16(const void* gsrc, void* ldst){
  __builtin_amdgcn_global_load_lds(
      (const __attribute__((address_space(1))) unsigned int*)gsrc,
      (__attribute__((address_space(3))) unsigned int*)(unsigned int)(unsigned long long)ldst,
      16, 0, 0);
}

// ===== convert: fp32 [b][d][m] -> split-bf16 hi/lo planes in 16B granules =====
// Spare duty: blocks with linear id < 641 also zero the w-slices + barrier region
// (needed fresh every launch; runs before sinkhorn_kernel in stream order).
__global__ __launch_bounds__(256) void convert_kernel(const float* __restrict__ se,
                                                      const float* __restrict__ te,
                                                      uint4* __restrict__ Ah, uint4* __restrict__ Al,
                                                      uint4* __restrict__ Bh, uint4* __restrict__ Bl,
                                                      float* __restrict__ zbase, int zcount)
{
  const int t  = threadIdx.x;
  const int mb = blockIdx.x;            // 0..7   (m chunk of 256)
  const int g  = blockIdx.y;            // 0..31  (k-octet)
  const int z  = blockIdx.z;            // 0..31: b = z&15, op = z>>4
  const int b  = z & 15, op = z >> 4;
  const int zb = blockIdx.x + 8*(blockIdx.y + 32*blockIdx.z);
  {
    int idx = zb*256 + t;
    if (idx < zcount) zbase[idx] = 0.0f;
  }
  const int m  = mb*256 + t;
  const float* src = (op ? te : se) + (size_t)b*D_*M_ + (size_t)g*8*M_ + m;
  float x[8];
  #pragma unroll
  for (int j=0;j<8;j++) x[j] = src[(size_t)j*M_];
  unsigned int hw[4], lw[4];
  #pragma unroll
  for (int p=0;p<4;p++){
    float a0 = x[2*p], a1 = x[2*p+1];
    unsigned short h0 = f2bf(a0), h1 = f2bf(a1);
    unsigned short q0 = f2bf(a0 - bf2f(h0)), q1 = f2bf(a1 - bf2f(h1));
    hw[p] = (unsigned)h0 | ((unsigned)h1<<16);
    lw[p] = (unsigned)q0 | ((unsigned)q1<<16);
  }
  const size_t gi = (size_t)(b*32 + g)*2048 + m;
  uint4* Ph = op ? Bh : Ah;
  uint4* Pl = op ? Bl : Al;
  Ph[gi] = *(const uint4*)hw;
  Pl[gi] = *(const uint4*)lw;
}

__global__ __launch_bounds__(256) void zero_kernel(float* __restrict__ p, int n){
  int i = blockIdx.x*256 + threadIdx.x;
  if (i < n) p[i] = 0.0f;
}

// ===== fast GEMM: pre-converted planes + global_load_lds staging =====
__global__ __launch_bounds__(256) void gemm_fast(const uint4* __restrict__ Ah,
                                                 const uint4* __restrict__ Al,
                                                 const uint4* __restrict__ Bh,
                                                 const uint4* __restrict__ Bl,
                                                 float* __restrict__ S)
{
  __shared__ unsigned int sAh[2048], sAl[2048], sBh[2048], sBl[2048];
  const int b  = blockIdx.z;
  const int mb = blockIdx.y;
  const int nb = blockIdx.x;
  const int t    = threadIdx.x;
  const int wave = t >> 6, lane = t & 63;
  const int wy = wave >> 1, wx = wave & 1;
  const int quad = lane >> 4, l15 = lane & 15;

  f32x4 acc[4][4] = {};

  for (int kc=0; kc<8; kc++){
    __syncthreads();
    #pragma unroll
    for (int r=0;r<2;r++){
      const int i  = r*256 + t;            // linear granule 0..511
      const int gq = i >> 7, m = i & 127;
      const size_t rowg = (size_t)(b*32 + kc*4 + gq)*2048;
      gll16(Ah + rowg + mb*128 + m, (char*)sAh + (size_t)i*16);
      gll16(Al + rowg + mb*128 + m, (char*)sAl + (size_t)i*16);
      gll16(Bh + rowg + nb*128 + m, (char*)sBh + (size_t)i*16);
      gll16(Bl + rowg + nb*128 + m, (char*)sBl + (size_t)i*16);
    }
    __syncthreads();
    bf16x8 ah[4], al[4], bh[4], bl[4];
    #pragma unroll
    for (int rt=0;rt<4;rt++){
      int ra = (quad*128 + wy*64 + rt*16 + l15)*4;
      int rb = (quad*128 + wx*64 + rt*16 + l15)*4;
      ah[rt] = *(const bf16x8*)&sAh[ra];
      al[rt] = *(const bf16x8*)&sAl[ra];
      bh[rt] = *(const bf16x8*)&sBh[rb];
      bl[rt] = *(const bf16x8*)&sBl[rb];
    }
    #pragma unroll
    for (int rt=0;rt<4;rt++)
      #pragma unroll
      for (int ct=0;ct<4;ct++){
        acc[rt][ct] = __builtin_amdgcn_mfma_f32_16x16x32_bf16(ah[rt], bh[ct], acc[rt][ct], 0,0,0);
        acc[rt][ct] = __builtin_amdgcn_mfma_f32_16x16x32_bf16(ah[rt], bl[ct], acc[rt][ct], 0,0,0);
        acc[rt][ct] = __builtin_amdgcn_mfma_f32_16x16x32_bf16(al[rt], bh[ct], acc[rt][ct], 0,0,0);
      }
  }
  const float sc = 0.0625f;   // 1/sqrt(256)
  #pragma unroll
  for (int rt=0;rt<4;rt++){
    #pragma unroll
    for (int r=0;r<4;r++){
      int m = mb*128 + wy*64 + rt*16 + quad*4 + r;
      float* rowp = S + (size_t)(b*M_ + m)*N_;
      #pragma unroll
      for (int ct=0;ct<4;ct++){
        int n = nb*128 + wx*64 + ct*16 + l15;
        rowp[n] = acc[rt][ct][r] * sc;
      }
    }
  }
}

// ===== fallback GEMM (inline conversion) — used only if ws too small =====
__global__ __launch_bounds__(256) void gemm_kernel(const float* __restrict__ se,
                                                   const float* __restrict__ te,
                                                   float* __restrict__ S)
{
  __shared__ unsigned int Ah[2048], Al[2048], Bh[2048], Bl[2048];
  const int b  = blockIdx.z;
  const int mb = blockIdx.y;
  const int nb = blockIdx.x;
  const int t    = threadIdx.x;
  const int wave = t >> 6, lane = t & 63;
  const int wy = wave >> 1, wx = wave & 1;
  const int quad = lane >> 4, l15 = lane & 15;
  const int ml  = t & 127;
  const int dh  = t >> 7;

  f32x4 acc[4][4] = {};

  const float* Abase = se + (size_t)b*D_*M_ + mb*128 + ml;
  const float* Bbase = te + (size_t)b*D_*M_ + nb*128 + ml;

  for (int kc=0; kc<8; kc++){
    __syncthreads();
    {
      float x[16];
      #pragma unroll
      for (int j=0;j<16;j++) x[j] = Abase[(size_t)(kc*32 + dh*16 + j)*M_];
      #pragma unroll
      for (int gi=0; gi<2; gi++){
        unsigned int hw[4], lw[4];
        #pragma unroll
        for (int p=0;p<4;p++){
          float a0 = x[gi*8+2*p], a1 = x[gi*8+2*p+1];
          unsigned short h0 = f2bf(a0), h1 = f2bf(a1);
          unsigned short q0 = f2bf(a0 - bf2f(h0)), q1 = f2bf(a1 - bf2f(h1));
          hw[p] = (unsigned)h0 | ((unsigned)h1<<16);
          lw[p] = (unsigned)q0 | ((unsigned)q1<<16);
        }
        int idx = ((dh*2+gi)*128 + ml)*4;
        *(uint4*)&Ah[idx] = *(uint4*)hw;
        *(uint4*)&Al[idx] = *(uint4*)lw;
      }
    }
    {
      float x[16];
      #pragma unroll
      for (int j=0;j<16;j++) x[j] = Bbase[(size_t)(kc*32 + dh*16 + j)*M_];
      #pragma unroll
      for (int gi=0; gi<2; gi++){
        unsigned int hw[4], lw[4];
        #pragma unroll
        for (int p=0;p<4;p++){
          float a0 = x[gi*8+2*p], a1 = x[gi*8+2*p+1];
          unsigned short h0 = f2bf(a0), h1 = f2bf(a1);
          unsigned short q0 = f2bf(a0 - bf2f(h0)), q1 = f2bf(a1 - bf2f(h1));
          hw[p] = (unsigned)h0 | ((unsigned)h1<<16);
          lw[p] = (unsigned)q0 | ((unsigned)q1<<16);
        }
        int idx = ((dh*2+gi)*128 + ml)*4;
        *(uint4*)&Bh[idx] = *(uint4*)hw;
        *(uint4*)&Bl[idx] = *(uint4*)lw;
      }
    }
    __syncthreads();
    bf16x8 ah[4], al[4], bh[4], bl[4];
    #pragma unroll
    for (int rt=0;rt<4;rt++){
      int ra = (quad*128 + wy*64 + rt*16 + l15)*4;
      int rb = (quad*128 + wx*64 + rt*16 + l15)*4;
      ah[rt] = *(const bf16x8*)&Ah[ra];
      al[rt] = *(const bf16x8*)&Al[ra];
      bh[rt] = *(const bf16x8*)&Bh[rb];
      bl[rt] = *(const bf16x8*)&Bl[rb];
    }
    #pragma unroll
    for (int rt=0;rt<4;rt++)
      #pragma unroll
      for (int ct=0;ct<4;ct++){
        acc[rt][ct] = __builtin_amdgcn_mfma_f32_16x16x32_bf16(ah[rt], bh[ct], acc[rt][ct], 0,0,0);
        acc[rt][ct] = __builtin_amdgcn_mfma_f32_16x16x32_bf16(ah[rt], bl[ct], acc[rt][ct], 0,0,0);
        acc[rt][ct] = __builtin_amdgcn_mfma_f32_16x16x32_bf16(al[rt], bh[ct], acc[rt][ct], 0,0,0);
      }
  }
  const float sc = 0.0625f;
  #pragma unroll
  for (int rt=0;rt<4;rt++){
    #pragma unroll
    for (int r=0;r<4;r++){
      int m = mb*128 + wy*64 + rt*16 + quad*4 + r;
      float* rowp = S + (size_t)(b*M_ + m)*N_;
      #pragma unroll
      for (int ct=0;ct<4;ct++){
        int n = nb*128 + wx*64 + ct*16 + l15;
        rowp[n] = acc[rt][ct][r] * sc;
      }
    }
  }
}

// ===== stats: per-row lse; K̂=exp((s-lse)/rho) stored fp16 in-place (front 4KB);
//       y0 = sum of the STORED fp16 K̂ =====
__global__ __launch_bounds__(256) void stats_kernel(float* __restrict__ S,
                                                    const float* __restrict__ rho,
                                                    float* __restrict__ y0)
{
  const int b = blockIdx.y;
  const int m = blockIdx.x*4 + (threadIdx.x>>6);
  const int lane = threadIdx.x & 63;
  const float invrho = 1.0f / fmaxf(rho[0], EPSF);
  float* row = S + (size_t)(b*M_ + m)*N_;
  const float4* row4 = (const float4*)row;
  float4 vals[8];
  float mx = -3.4e38f;
  #pragma unroll
  for (int k=0;k<8;k++){
    float4 v = row4[lane + 64*k];
    vals[k] = v;
    mx = fmaxf(mx, fmaxf(fmaxf(v.x,v.y), fmaxf(v.z,v.w)));
  }
  mx = wredmax(mx);
  float e1=0.0f;
  #pragma unroll
  for (int k=0;k<8;k++){
    float4 v = vals[k];
    e1 += __expf(v.x-mx)+__expf(v.y-mx)+__expf(v.z-mx)+__expf(v.w-mx);
  }
  e1 = wredsum(e1);
  const float l = mx + __logf(e1);
  uint2* rowh2 = (uint2*)row;
  float y2 = 0.0f;
  #pragma unroll
  for (int k=0;k<8;k++){
    float4 v = vals[k];
    unsigned short h0 = f2h(__expf((v.x-l)*invrho));
    unsigned short h1 = f2h(__expf((v.y-l)*invrho));
    unsigned short h2 = f2h(__expf((v.z-l)*invrho));
    unsigned short h3 = f2h(__expf((v.w-l)*invrho));
    y2 += h2f(h0)+h2f(h1)+h2f(h2)+h2f(h3);
    uint2 pk;
    pk.x = (unsigned)h0 | ((unsigned)h1<<16);
    pk.y = (unsigned)h2 | ((unsigned)h3<<16);
    rowh2[lane + 64*k] = pk;
  }
  y2 = wredsum(y2);
  if (lane==0) y0[b*M_+m] = y2;
}

// ===== persistent Sinkhorn: init + it0-col + 4x(vupd+row+col) + final vupd =====
// Grid dim3(NCH,16) = 512 blocks <= 2 blocks/CU (guaranteed resident via
// __launch_bounds__(256,2) per the capacity rule).  Per-batch barriers only:
// batches are fully independent.  v,g replicated per block (bit-identical
// reduction order across blocks); u rows are block-private.
// w uses 5 per-iteration slices (no reset hazard); zeroed by convert_kernel.
#define VIDX(j) ((j) + (((j)>>5)<<2))    // +4 floats per 32: 16B-aligned pad

__device__ __forceinline__ void batch_barrier(unsigned int* ctr){
  __syncthreads();
  if (threadIdx.x==0){
    __hip_atomic_fetch_add(ctr, 1u, __ATOMIC_RELEASE, __HIP_MEMORY_SCOPE_AGENT);
    while (__hip_atomic_load(ctr, __ATOMIC_ACQUIRE, __HIP_MEMORY_SCOPE_AGENT) < NCH)
      __builtin_amdgcn_s_sleep(2);
  }
  __syncthreads();
}

__global__ __launch_bounds__(256, 2) void sinkhorn_kernel(const float* __restrict__ S,
                                                          const float* __restrict__ y0,
                                                          float* __restrict__ u,
                                                          float* __restrict__ v,
                                                          float* __restrict__ g,
                                                          float* __restrict__ wbuf,
                                                          unsigned int* __restrict__ bar)
{
  __shared__ float vloc[2304];        // 2048 + pad
  __shared__ float wsh[4][2048];
  __shared__ float redsh[4];
  const int b = blockIdx.y, chunk = blockIdx.x;
  const int t = threadIdx.x, wid = t>>6, lane = t&63;
  const int i0 = chunk*64;

  // ---- init: g0 = 1/sum(y0[b]); u0 for my rows; v = 1 ----
  float s0 = 0.0f;
  for (int i=t;i<N_;i+=256) s0 += y0[b*M_+i];
  s0 = wredsum(s0);
  if (lane==0) redsh[wid]=s0;
  __syncthreads();
  float gcur = 1.0f / fmaxf(redsh[0]+redsh[1]+redsh[2]+redsh[3], EPSF);
  float u_w[16];
  #pragma unroll
  for (int r=0;r<16;r++){
    float ys = y0[b*M_ + i0 + wid*16 + r];
    u_w[r] = fminf(AVAL / fmaxf(gcur*ys, EPSF), 1.0f);
  }
  for (int i=t;i<N_;i+=256) vloc[VIDX(i)] = 1.0f;
  // (no sync needed yet: vloc first read is after barrier 0)

  float acc[32];

  // ---- it0: col only (u0 is the first row update) -> w slice 0 ----
  #pragma unroll
  for (int k=0;k<32;k++) acc[k]=0.0f;
  for (int r=0;r<16;r++){
    const uint4* rowh = (const uint4*)(S + (size_t)(b*M_ + i0 + wid*16 + r)*N_);
    const float un = u_w[r];
    #pragma unroll
    for (int k=0;k<4;k++){
      uint4 su = rowh[lane + 64*k];
      acc[k*8+0] += un*h2f((unsigned short)(su.x&0xffff));
      acc[k*8+1] += un*h2f((unsigned short)(su.x>>16));
      acc[k*8+2] += un*h2f((unsigned short)(su.y&0xffff));
      acc[k*8+3] += un*h2f((unsigned short)(su.y>>16));
      acc[k*8+4] += un*h2f((unsigned short)(su.z&0xffff));
      acc[k*8+5] += un*h2f((unsigned short)(su.z>>16));
      acc[k*8+6] += un*h2f((unsigned short)(su.w&0xffff));
      acc[k*8+7] += un*h2f((unsigned short)(su.w>>16));
    }
  }
  {
    #pragma unroll
    for (int k=0;k<4;k++)
      #pragma unroll
      for (int e=0;e<8;e++)
        wsh[wid][(lane+64*k)*8+e] = acc[k*8+e];
    __syncthreads();
    float* w0 = wbuf + b*N_;
    #pragma unroll
    for (int e=0;e<8;e++){
      int j = t*8+e;
      atomicAdd(&w0[j], wsh[0][j]+wsh[1][j]+wsh[2][j]+wsh[3][j]);
    }
  }
  batch_barrier(&bar[b*8 + 0]);

  // ---- it = 1..4: local vupd (redundant, deterministic) + fused row/col ----
  for (int it=1; it<=4; ++it){
    const float* wprev = wbuf + (size_t)(it-1)*B_*N_ + b*N_;
    float part = 0.0f;
    for (int i=t;i<N_;i+=256){
      float wj = __hip_atomic_load(&wprev[i], __ATOMIC_RELAXED, __HIP_MEMORY_SCOPE_AGENT);
      float vj = vloc[VIDX(i)];
      float c  = fminf(AVAL / fmaxf(gcur*vj*wj, EPSF), 1.0f);
      vj *= c;
      vloc[VIDX(i)] = vj;
      part += wj*vj;
    }
    part = wredsum(part);
    if (lane==0) redsh[wid]=part;
    __syncthreads();
    {
      float tot = gcur*(redsh[0]+redsh[1]+redsh[2]+redsh[3]);
      gcur = gcur / fmaxf(tot, EPSF);
    }
    // fused row update + col accumulation (one K̂ read)
    #pragma unroll
    for (int k=0;k<32;k++) acc[k]=0.0f;
    for (int r=0;r<16;r++){
      const uint4* rowh = (const uint4*)(S + (size_t)(b*M_ + i0 + wid*16 + r)*N_);
      float sv[32];
      float dot = 0.0f;
      #pragma unroll
      for (int k=0;k<4;k++){
        uint4 su = rowh[lane + 64*k];
        const int pb = VIDX((lane+64*k)*8);
        float4 v0 = *(const float4*)&vloc[pb];
        float4 v1 = *(const float4*)&vloc[pb+4];
        float q0 = h2f((unsigned short)(su.x&0xffff));
        float q1 = h2f((unsigned short)(su.x>>16));
        float q2 = h2f((unsigned short)(su.y&0xffff));
        float q3 = h2f((unsigned short)(su.y>>16));
        float q4 = h2f((unsigned short)(su.z&0xffff));
        float q5 = h2f((unsigned short)(su.z>>16));
        float q6 = h2f((unsigned short)(su.w&0xffff));
        float q7 = h2f((unsigned short)(su.w>>16));
        dot += q0*v0.x + q1*v0.y + q2*v0.z + q3*v0.w
             + q4*v1.x + q5*v1.y + q6*v1.z + q7*v1.w;
        sv[k*8+0]=q0; sv[k*8+1]=q1; sv[k*8+2]=q2; sv[k*8+3]=q3;
        sv[k*8+4]=q4; sv[k*8+5]=q5; sv[k*8+6]=q6; sv[k*8+7]=q7;
      }
      dot = wredsum(dot);
      float ui = u_w[r];
      float rs = gcur*ui*dot;
      float un = ui * fminf(AVAL / fmaxf(rs, EPSF), 1.0f);
      u_w[r] = un;
      #pragma unroll
      for (int k=0;k<32;k++) acc[k] += un * sv[k];
    }
    __syncthreads();   // wsh reuse safe (all past previous combine via barrier)
    #pragma unroll
    for (int k=0;k<4;k++)
      #pragma unroll
      for (int e=0;e<8;e++)
        wsh[wid][(lane+64*k)*8+e] = acc[k*8+e];
    __syncthreads();
    float* wcur = wbuf + (size_t)it*B_*N_ + b*N_;
    #pragma unroll
    for (int e=0;e<8;e++){
      int j = t*8+e;
      atomicAdd(&wcur[j], wsh[0][j]+wsh[1][j]+wsh[2][j]+wsh[3][j]);
    }
    batch_barrier(&bar[b*8 + it]);
  }

  // ---- final vupd (w slice 4) -> v5, g5; write back u, v, g ----
  {
    const float* wprev = wbuf + (size_t)4*B_*N_ + b*N_;
    float part = 0.0f;
    for (int i=t;i<N_;i+=256){
      float wj = __hip_atomic_load(&wprev[i], __ATOMIC_RELAXED, __HIP_MEMORY_SCOPE_AGENT);
      float vj = vloc[VIDX(i)];
      float c  = fminf(AVAL / fmaxf(gcur*vj*wj, EPSF), 1.0f);
      vj *= c;
      vloc[VIDX(i)] = vj;
      part += wj*vj;
    }
    part = wredsum(part);
    if (lane==0) redsh[wid]=part;
    __syncthreads();
    float tot = gcur*(redsh[0]+redsh[1]+redsh[2]+redsh[3]);
    gcur = gcur / fmaxf(tot, EPSF);
  }
  if (lane==0){
    #pragma unroll
    for (int r=0;r<16;r++) u[b*M_ + i0 + wid*16 + r] = u_w[r];
  }
  if (chunk==0){
    for (int i=t;i<N_;i+=256) v[b*N_+i] = vloc[VIDX(i)];
    if (t==0) g[b] = gcur;
  }
}

// ---- final: matches fp32 overwrite rows in place; fused rowsum + matches@t^T ----
__global__ __launch_bounds__(256) void final_kernel(float* __restrict__ S,
                                                    const float* __restrict__ u,
                                                    const float* __restrict__ v,
                                                    const float* __restrict__ g,
                                                    const float* __restrict__ tgt,
                                                    float* __restrict__ rowsum,
                                                    float* __restrict__ wref)
{
  const int b = blockIdx.y;
  const int m = blockIdx.x*4 + (threadIdx.x>>6);
  const int lane = threadIdx.x & 63;
  const float gu = g[b]*u[b*M_+m];
  float* row = S + (size_t)(b*M_ + m)*N_;
  const uint4* rowh = (const uint4*)row;
  uint4 su[4];
  #pragma unroll
  for (int k=0;k<4;k++) su[k] = rowh[lane + 64*k];
  __builtin_amdgcn_s_waitcnt(0);
  float4* rowf = (float4*)row;
  const float4* vp = (const float4*)(v + (size_t)b*N_);
  const float4* t0 = (const float4*)(tgt + ((size_t)b*3+0)*N_);
  const float4* t1 = (const float4*)(tgt + ((size_t)b*3+1)*N_);
  const float4* t2 = (const float4*)(tgt + ((size_t)b*3+2)*N_);
  float rs=0.0f, a0=0.0f, a1=0.0f, a2=0.0f;
  #pragma unroll
  for (int k=0;k<4;k++){
    float s[8] = {h2f((unsigned short)(su[k].x&0xffff)), h2f((unsigned short)(su[k].x>>16)),
                  h2f((unsigned short)(su[k].y&0xffff)), h2f((unsigned short)(su[k].y>>16)),
                  h2f((unsigned short)(su[k].z&0xffff)), h2f((unsigned short)(su[k].z>>16)),
                  h2f((unsigned short)(su[k].w&0xffff)), h2f((unsigned short)(su[k].w>>16))};
    int i2 = (lane+64*k)*2;
    #pragma unroll
    for (int h=0;h<2;h++){
      float4 v4 = vp[i2+h];
      float4 q0 = t0[i2+h], q1 = t1[i2+h], q2 = t2[i2+h];
      float m0 = gu*s[h*4+0]*v4.x;
      float m1 = gu*s[h*4+1]*v4.y;
      float m2 = gu*s[h*4+2]*v4.z;
      float m3 = gu*s[h*4+3]*v4.w;
      rs += m0+m1+m2+m3;
      a0 += m0*q0.x + m1*q0.y + m2*q0.z + m3*q0.w;
      a1 += m0*q1.x + m1*q1.y + m2*q1.z + m3*q1.w;
      a2 += m0*q2.x + m1*q2.y + m2*q2.z + m3*q2.w;
      rowf[i2+h] = make_float4(m0,m1,m2,m3);
    }
  }
  rs = wredsum(rs); a0=wredsum(a0); a1=wredsum(a1); a2=wredsum(a2);
  if (lane==0){
    rowsum[b*M_+m] = rs;
    float inv = 1.0f/(rs+1e-6f);
    size_t o = ((size_t)b*M_+m)*3;
    wref[o]=a0*inv; wref[o+1]=a1*inv; wref[o+2]=a2*inv;
  }
}

// ---------------- 3x3 Kabsch via Jacobi on cov^T cov (verified R1) ----------------
__device__ __forceinline__ void mat3_svd_rot(const float cov[3][3], float R[3][3])
{
  float mx = 1e-30f;
  for (int p=0;p<3;p++) for (int q=0;q<3;q++) mx = fmaxf(mx, fabsf(cov[p][q]));
  const float inv = 1.0f/mx;
  float Cm[3][3];
  for (int p=0;p<3;p++) for (int q=0;q<3;q++) Cm[p][q]=cov[p][q]*inv;
  float G[3][3];
  for (int p=0;p<3;p++)
    for (int q=0;q<3;q++)
      G[p][q] = Cm[0][p]*Cm[0][q] + Cm[1][p]*Cm[1][q] + Cm[2][p]*Cm[2][q];
  float V[3][3] = {{1,0,0},{0,1,0},{0,0,1}};
  const int PP[3]={0,0,1}, QQ[3]={1,2,2};
  for (int sweep=0;sweep<12;sweep++){
    for (int r=0;r<3;r++){
      int p=PP[r], q=QQ[r];
      float apq = G[p][q];
      if (fabsf(apq) < 1e-20f) continue;
      float tau = (G[q][q]-G[p][p])/(2.0f*apq);
      float tt  = (tau>=0.0f?1.0f:-1.0f)/(fabsf(tau)+sqrtf(1.0f+tau*tau));
      float cc  = 1.0f/sqrtf(1.0f+tt*tt);
      float ss  = tt*cc;
      for (int k=0;k<3;k++){ float gkp=G[k][p], gkq=G[k][q]; G[k][p]=cc*gkp-ss*gkq; G[k][q]=ss*gkp+cc*gkq; }
      for (int k=0;k<3;k++){ float gpk=G[p][k], gqk=G[q][k]; G[p][k]=cc*gpk-ss*gqk; G[q][k]=ss*gpk+cc*gqk; }
      for (int k=0;k<3;k++){ float vkp=V[k][p], vkq=V[k][q]; V[k][p]=cc*vkp-ss*vkq; V[k][q]=ss*vkp+cc*vkq; }
    }
  }
  float ev[3]={G[0][0],G[1][1],G[2][2]};
  int i0=0,i1=1,i2=2,tmp;
  if (ev[i0]<ev[i1]){tmp=i0;i0=i1;i1=tmp;}
  if (ev[i0]<ev[i2]){tmp=i0;i0=i2;i2=tmp;}
  if (ev[i1]<ev[i2]){tmp=i1;i1=i2;i2=tmp;}
  const int idx[3]={i0,i1,i2};
  float Vs[3][3];
  for (int k=0;k<3;k++) for (int i=0;i<3;i++) Vs[i][k]=V[i][idx[k]];
  float U[3][3]; float nrm[3];
  for (int k=0;k<3;k++){
    float ux = Cm[0][0]*Vs[0][k]+Cm[0][1]*Vs[1][k]+Cm[0][2]*Vs[2][k];
    float uy = Cm[1][0]*Vs[0][k]+Cm[1][1]*Vs[1][k]+Cm[1][2]*Vs[2][k];
    float uz = Cm[2][0]*Vs[0][k]+Cm[2][1]*Vs[1][k]+Cm[2][2]*Vs[2][k];
    float n = sqrtf(ux*ux+uy*uy+uz*uz);
    nrm[k]=n;
    float in = (n>1e-20f)?1.0f/n:0.0f;
    U[0][k]=ux*in; U[1][k]=uy*in; U[2][k]=uz*in;
  }
  if (nrm[2] < 1e-6f*fmaxf(nrm[0],1e-20f)){
    U[0][2]=U[1][0]*U[2][1]-U[2][0]*U[1][1];
    U[1][2]=U[2][0]*U[0][1]-U[0][0]*U[2][1];
    U[2][2]=U[0][0]*U[1][1]-U[1][0]*U[0][1];
  }
  float detC = Cm[0][0]*(Cm[1][1]*Cm[2][2]-Cm[1][2]*Cm[2][1])
             - Cm[0][1]*(Cm[1][0]*Cm[2][2]-Cm[1][2]*Cm[2][0])
             + Cm[0][2]*(Cm[1][0]*Cm[2][1]-Cm[1][1]*Cm[2][0]);
  float d2 = (detC>0.0f)?1.0f:-1.0f;
  for (int p=0;p<3;p++)
    for (int q=0;q<3;q++)
      R[p][q] = Vs[p][0]*U[q][0] + Vs[p][1]*U[q][1] + d2*Vs[p][2]*U[q][2];
}

__global__ __launch_bounds__(256) void rigid_kernel(const float* __restrict__ src,
                                                    const float* __restrict__ wref,
                                                    const float* __restrict__ rowsum,
                                                    float* __restrict__ out)
{
  const int b = blockIdx.x; const int t = threadIdx.x;
  float acc[16];
  #pragma unroll
  for (int k=0;k<16;k++) acc[k]=0.0f;
  for (int i=t;i<M_;i+=256){
    float wgt = rowsum[b*M_+i];
    float ax = src[((size_t)b*3+0)*M_+i];
    float ay = src[((size_t)b*3+1)*M_+i];
    float az = src[((size_t)b*3+2)*M_+i];
    const float* wr = wref + ((size_t)b*M_+i)*3;
    float bx=wr[0], by=wr[1], bz=wr[2];
    acc[0]+=wgt;
    acc[1]+=wgt*ax; acc[2]+=wgt*ay; acc[3]+=wgt*az;
    acc[4]+=wgt*bx; acc[5]+=wgt*by; acc[6]+=wgt*bz;
    acc[7] +=wgt*ax*bx; acc[8] +=wgt*ax*by; acc[9] +=wgt*ax*bz;
    acc[10]+=wgt*ay*bx; acc[11]+=wgt*ay*by; acc[12]+=wgt*ay*bz;
    acc[13]+=wgt*az*bx; acc[14]+=wgt*az*by; acc[15]+=wgt*az*bz;
  }
  __shared__ float red[4][16];
  const int wid = t>>6, lane = t&63;
  #pragma unroll
  for (int k=0;k<16;k++){
    float v = acc[k];
    #pragma unroll
    for (int off=32; off; off>>=1) v += __shfl_xor(v, off);
    if (lane==0) red[wid][k]=v;
  }
  __syncthreads();
  if (t==0){
    float s[16];
    #pragma unroll
    for (int k=0;k<16;k++) s[k]=red[0][k]+red[1][k]+red[2][k]+red[3][k];
    float wsum = s[0];
    float denom = wsum + 1e-6f;
    float ca[3]={s[1]/denom, s[2]/denom, s[3]/denom};
    float cb[3]={s[4]/denom, s[5]/denom, s[6]/denom};
    float sw = wsum/denom;
    float cov[3][3];
    for (int p=0;p<3;p++)
      for (int q=0;q<3;q++)
        cov[p][q] = s[7+p*3+q]/denom + (sw-2.0f)*ca[p]*cb[q];
    float R[3][3];
    mat3_svd_rot(cov, R);
    float tr[3];
    for (int p=0;p<3;p++)
      tr[p] = -(R[p][0]*ca[0]+R[p][1]*ca[1]+R[p][2]*ca[2]) + cb[p];
    for (int p=0;p<3;p++)
      for (int q=0;q<3;q++)
        out[b*9 + p*3 + q] = R[p][q];
    for (int p=0;p<3;p++)
      out[144 + b*3 + p] = tr[p];
  }
}

extern "C" void kernel_launch(void* const* d_in, const int* in_sizes, int n_in,
                              void* d_out, int out_size, void* d_ws, size_t ws_size,
                              hipStream_t stream)
{
  const float* se  = (const float*)d_in[0];
  const float* te  = (const float*)d_in[1];
  const float* src = (const float*)d_in[2];
  const float* tgt = (const float*)d_in[3];
  const float* rho = (const float*)d_in[4];
  float* out = (float*)d_out;
  float* S   = out + 192;                 // matches region doubles as S / K̂ scratch
  float* ws  = (float*)d_ws;

  // ws layout (floats)
  float*        y0   = ws;                         // 32768 (also final rowsum)
  float*        u    = ws + 32768;                 // 32768
  float*        v    = ws + 65536;                 // 32768
  float*        g    = ws + 98304;                 // 16
  float*        wref = ws + 98320;                 // 98304 -> ends 196624
  float*        wbuf = ws + 196624;                // 5*32768 = 163840 -> ends 360464
  unsigned int* bar  = (unsigned int*)(ws + 360464); // 128 u32 -> ends 360592
  const int     ZCNT = 163840 + 128;               // wbuf + bar zero region
  float*        zb   = wbuf;

  // split-bf16 operand planes
  const size_t PLANE_G     = (size_t)16*32*2048;          // granules per plane
  const size_t PLANE_BYTES = PLANE_G*16;                  // 16.78 MB
  const size_t PLANE_OFF   = (size_t)360592*4;            // byte 1442368, 16B-aligned
  const size_t need        = PLANE_OFF + 4*PLANE_BYTES;   // ~68.6 MB

  if (ws_size >= need){
    uint4* Ah = (uint4*)((char*)d_ws + PLANE_OFF);
    uint4* Al = Ah + PLANE_G;
    uint4* Bh = Al + PLANE_G;
    uint4* Bl = Bh + PLANE_G;
    convert_kernel<<<dim3(8,32,32),256,0,stream>>>(se,te,Ah,Al,Bh,Bl,zb,ZCNT);
    gemm_fast     <<<dim3(16,16,16),256,0,stream>>>(Ah,Al,Bh,Bl,S);
  } else {
    zero_kernel   <<<dim3((ZCNT+255)/256),256,0,stream>>>(zb,ZCNT);
    gemm_kernel   <<<dim3(16,16,16),256,0,stream>>>(se,te,S);
  }
  stats_kernel   <<<dim3(512,16),  256,0,stream>>>(S,rho,y0);
  sinkhorn_kernel<<<dim3(NCH,16),  256,0,stream>>>(S,y0,u,v,g,wbuf,bar);
  final_kernel   <<<dim3(512,16),  256,0,stream>>>(S,u,v,g,tgt,y0,wref);
  rigid_kernel   <<<dim3(16),      256,0,stream>>>(src,wref,y0,out);
}

// Round 4
// 914.654 us; speedup vs baseline: 1.7831x; 1.7831x over previous
//
#include <hip/hip_runtime.h>
#include <math.h>

#define B_ 16
#define D_ 256
#define M_ 2048
#define N_ 2048
#define EPSF 1e-8f
#define AVAL (1.0f/2048.0f)   // a_i = 1/M = b_j = 1/N ; m = 1
#define NCH 32                // row-chunks (blocks) per batch in sinkhorn_kernel

typedef __bf16  bf16x8 __attribute__((ext_vector_type(8)));
typedef float   f32x4  __attribute__((ext_vector_type(4)));

__device__ __forceinline__ float wredsum(float x){
  #pragma unroll
  for (int off=32; off; off>>=1) x += __shfl_xor(x, off);
  return x;
}
__device__ __forceinline__ float wredmax(float x){
  #pragma unroll
  for (int off=32; off; off>>=1) x = fmaxf(x, __shfl_xor(x, off));
  return x;
}
__device__ __forceinline__ unsigned short f2bf(float x){
  unsigned int v = __float_as_uint(x);
  unsigned int r = (v + 0x7fffu + ((v>>16)&1u)) >> 16;   // RNE
  return (unsigned short)r;
}
__device__ __forceinline__ float bf2f(unsigned short u){ return __uint_as_float(((unsigned int)u)<<16); }
__device__ __forceinline__ float h2f(unsigned short h){
  _Float16 x; __builtin_memcpy(&x,&h,2); return (float)x;
}
__device__ __forceinline__ unsigned short f2h(float x){
  _Float16 h = (_Float16)x; unsigned short u; __builtin_memcpy(&u,&h,2); return u;
}

// async global->LDS, 16B per lane.
__device__ __forceinline__ void gll16(const void* gsrc, void* ldst){
  __builtin_amdgcn_global_load_lds(
      (const __attribute__((address_space(1))) unsigned int*)gsrc,
      (__attribute__((address_space(3))) unsigned int*)(unsigned int)(unsigned long long)ldst,
      16, 0, 0);
}

// ===== convert: fp32 [b][d][m] -> split-bf16 hi/lo planes in 16B granules =====
// Spare duty: blocks with linear id < ~641 also zero the w-slices + barrier region.
__global__ __launch_bounds__(256) void convert_kernel(const float* __restrict__ se,
                                                      const float* __restrict__ te,
                                                      uint4* __restrict__ Ah, uint4* __restrict__ Al,
                                                      uint4* __restrict__ Bh, uint4* __restrict__ Bl,
                                                      float* __restrict__ zbase, int zcount)
{
  const int t  = threadIdx.x;
  const int mb = blockIdx.x;            // 0..7   (m chunk of 256)
  const int g  = blockIdx.y;            // 0..31  (k-octet)
  const int z  = blockIdx.z;            // 0..31: b = z&15, op = z>>4
  const int b  = z & 15, op = z >> 4;
  const int zb = blockIdx.x + 8*(blockIdx.y + 32*blockIdx.z);
  {
    int idx = zb*256 + t;
    if (idx < zcount) zbase[idx] = 0.0f;
  }
  const int m  = mb*256 + t;
  const float* src = (op ? te : se) + (size_t)b*D_*M_ + (size_t)g*8*M_ + m;
  float x[8];
  #pragma unroll
  for (int j=0;j<8;j++) x[j] = src[(size_t)j*M_];
  unsigned int hw[4], lw[4];
  #pragma unroll
  for (int p=0;p<4;p++){
    float a0 = x[2*p], a1 = x[2*p+1];
    unsigned short h0 = f2bf(a0), h1 = f2bf(a1);
    unsigned short q0 = f2bf(a0 - bf2f(h0)), q1 = f2bf(a1 - bf2f(h1));
    hw[p] = (unsigned)h0 | ((unsigned)h1<<16);
    lw[p] = (unsigned)q0 | ((unsigned)q1<<16);
  }
  const size_t gi = (size_t)(b*32 + g)*2048 + m;
  uint4* Ph = op ? Bh : Ah;
  uint4* Pl = op ? Bl : Al;
  Ph[gi] = *(const uint4*)hw;
  Pl[gi] = *(const uint4*)lw;
}

__global__ __launch_bounds__(256) void zero_kernel(float* __restrict__ p, int n){
  int i = blockIdx.x*256 + threadIdx.x;
  if (i < n) p[i] = 0.0f;
}

// ===== fast GEMM: pre-converted planes + global_load_lds staging =====
__global__ __launch_bounds__(256) void gemm_fast(const uint4* __restrict__ Ah,
                                                 const uint4* __restrict__ Al,
                                                 const uint4* __restrict__ Bh,
                                                 const uint4* __restrict__ Bl,
                                                 float* __restrict__ S)
{
  __shared__ unsigned int sAh[2048], sAl[2048], sBh[2048], sBl[2048];
  const int b  = blockIdx.z;
  const int mb = blockIdx.y;
  const int nb = blockIdx.x;
  const int t    = threadIdx.x;
  const int wave = t >> 6, lane = t & 63;
  const int wy = wave >> 1, wx = wave & 1;
  const int quad = lane >> 4, l15 = lane & 15;

  f32x4 acc[4][4] = {};

  for (int kc=0; kc<8; kc++){
    __syncthreads();
    #pragma unroll
    for (int r=0;r<2;r++){
      const int i  = r*256 + t;            // linear granule 0..511
      const int gq = i >> 7, m = i & 127;
      const size_t rowg = (size_t)(b*32 + kc*4 + gq)*2048;
      gll16(Ah + rowg + mb*128 + m, (char*)sAh + (size_t)i*16);
      gll16(Al + rowg + mb*128 + m, (char*)sAl + (size_t)i*16);
      gll16(Bh + rowg + nb*128 + m, (char*)sBh + (size_t)i*16);
      gll16(Bl + rowg + nb*128 + m, (char*)sBl + (size_t)i*16);
    }
    __syncthreads();
    bf16x8 ah[4], al[4], bh[4], bl[4];
    #pragma unroll
    for (int rt=0;rt<4;rt++){
      int ra = (quad*128 + wy*64 + rt*16 + l15)*4;
      int rb = (quad*128 + wx*64 + rt*16 + l15)*4;
      ah[rt] = *(const bf16x8*)&sAh[ra];
      al[rt] = *(const bf16x8*)&sAl[ra];
      bh[rt] = *(const bf16x8*)&sBh[rb];
      bl[rt] = *(const bf16x8*)&sBl[rb];
    }
    #pragma unroll
    for (int rt=0;rt<4;rt++)
      #pragma unroll
      for (int ct=0;ct<4;ct++){
        acc[rt][ct] = __builtin_amdgcn_mfma_f32_16x16x32_bf16(ah[rt], bh[ct], acc[rt][ct], 0,0,0);
        acc[rt][ct] = __builtin_amdgcn_mfma_f32_16x16x32_bf16(ah[rt], bl[ct], acc[rt][ct], 0,0,0);
        acc[rt][ct] = __builtin_amdgcn_mfma_f32_16x16x32_bf16(al[rt], bh[ct], acc[rt][ct], 0,0,0);
      }
  }
  const float sc = 0.0625f;   // 1/sqrt(256)
  #pragma unroll
  for (int rt=0;rt<4;rt++){
    #pragma unroll
    for (int r=0;r<4;r++){
      int m = mb*128 + wy*64 + rt*16 + quad*4 + r;
      float* rowp = S + (size_t)(b*M_ + m)*N_;
      #pragma unroll
      for (int ct=0;ct<4;ct++){
        int n = nb*128 + wx*64 + ct*16 + l15;
        rowp[n] = acc[rt][ct][r] * sc;
      }
    }
  }
}

// ===== fallback GEMM (inline conversion) — used only if ws too small =====
__global__ __launch_bounds__(256) void gemm_kernel(const float* __restrict__ se,
                                                   const float* __restrict__ te,
                                                   float* __restrict__ S)
{
  __shared__ unsigned int Ah[2048], Al[2048], Bh[2048], Bl[2048];
  const int b  = blockIdx.z;
  const int mb = blockIdx.y;
  const int nb = blockIdx.x;
  const int t    = threadIdx.x;
  const int wave = t >> 6, lane = t & 63;
  const int wy = wave >> 1, wx = wave & 1;
  const int quad = lane >> 4, l15 = lane & 15;
  const int ml  = t & 127;
  const int dh  = t >> 7;

  f32x4 acc[4][4] = {};

  const float* Abase = se + (size_t)b*D_*M_ + mb*128 + ml;
  const float* Bbase = te + (size_t)b*D_*M_ + nb*128 + ml;

  for (int kc=0; kc<8; kc++){
    __syncthreads();
    {
      float x[16];
      #pragma unroll
      for (int j=0;j<16;j++) x[j] = Abase[(size_t)(kc*32 + dh*16 + j)*M_];
      #pragma unroll
      for (int gi=0; gi<2; gi++){
        unsigned int hw[4], lw[4];
        #pragma unroll
        for (int p=0;p<4;p++){
          float a0 = x[gi*8+2*p], a1 = x[gi*8+2*p+1];
          unsigned short h0 = f2bf(a0), h1 = f2bf(a1);
          unsigned short q0 = f2bf(a0 - bf2f(h0)), q1 = f2bf(a1 - bf2f(h1));
          hw[p] = (unsigned)h0 | ((unsigned)h1<<16);
          lw[p] = (unsigned)q0 | ((unsigned)q1<<16);
        }
        int idx = ((dh*2+gi)*128 + ml)*4;
        *(uint4*)&Ah[idx] = *(uint4*)hw;
        *(uint4*)&Al[idx] = *(uint4*)lw;
      }
    }
    {
      float x[16];
      #pragma unroll
      for (int j=0;j<16;j++) x[j] = Bbase[(size_t)(kc*32 + dh*16 + j)*M_];
      #pragma unroll
      for (int gi=0; gi<2; gi++){
        unsigned int hw[4], lw[4];
        #pragma unroll
        for (int p=0;p<4;p++){
          float a0 = x[gi*8+2*p], a1 = x[gi*8+2*p+1];
          unsigned short h0 = f2bf(a0), h1 = f2bf(a1);
          unsigned short q0 = f2bf(a0 - bf2f(h0)), q1 = f2bf(a1 - bf2f(h1));
          hw[p] = (unsigned)h0 | ((unsigned)h1<<16);
          lw[p] = (unsigned)q0 | ((unsigned)q1<<16);
        }
        int idx = ((dh*2+gi)*128 + ml)*4;
        *(uint4*)&Bh[idx] = *(uint4*)hw;
        *(uint4*)&Bl[idx] = *(uint4*)lw;
      }
    }
    __syncthreads();
    bf16x8 ah[4], al[4], bh[4], bl[4];
    #pragma unroll
    for (int rt=0;rt<4;rt++){
      int ra = (quad*128 + wy*64 + rt*16 + l15)*4;
      int rb = (quad*128 + wx*64 + rt*16 + l15)*4;
      ah[rt] = *(const bf16x8*)&Ah[ra];
      al[rt] = *(const bf16x8*)&Al[ra];
      bh[rt] = *(const bf16x8*)&Bh[rb];
      bl[rt] = *(const bf16x8*)&Bl[rb];
    }
    #pragma unroll
    for (int rt=0;rt<4;rt++)
      #pragma unroll
      for (int ct=0;ct<4;ct++){
        acc[rt][ct] = __builtin_amdgcn_mfma_f32_16x16x32_bf16(ah[rt], bh[ct], acc[rt][ct], 0,0,0);
        acc[rt][ct] = __builtin_amdgcn_mfma_f32_16x16x32_bf16(ah[rt], bl[ct], acc[rt][ct], 0,0,0);
        acc[rt][ct] = __builtin_amdgcn_mfma_f32_16x16x32_bf16(al[rt], bh[ct], acc[rt][ct], 0,0,0);
      }
  }
  const float sc = 0.0625f;
  #pragma unroll
  for (int rt=0;rt<4;rt++){
    #pragma unroll
    for (int r=0;r<4;r++){
      int m = mb*128 + wy*64 + rt*16 + quad*4 + r;
      float* rowp = S + (size_t)(b*M_ + m)*N_;
      #pragma unroll
      for (int ct=0;ct<4;ct++){
        int n = nb*128 + wx*64 + ct*16 + l15;
        rowp[n] = acc[rt][ct][r] * sc;
      }
    }
  }
}

// ===== stats: per-row lse; K̂=exp((s-lse)/rho) stored fp16 in-place (front 4KB);
//       y0 = sum of the STORED fp16 K̂ =====
__global__ __launch_bounds__(256) void stats_kernel(float* __restrict__ S,
                                                    const float* __restrict__ rho,
                                                    float* __restrict__ y0)
{
  const int b = blockIdx.y;
  const int m = blockIdx.x*4 + (threadIdx.x>>6);
  const int lane = threadIdx.x & 63;
  const float invrho = 1.0f / fmaxf(rho[0], EPSF);
  float* row = S + (size_t)(b*M_ + m)*N_;
  const float4* row4 = (const float4*)row;
  float4 vals[8];
  float mx = -3.4e38f;
  #pragma unroll
  for (int k=0;k<8;k++){
    float4 v = row4[lane + 64*k];
    vals[k] = v;
    mx = fmaxf(mx, fmaxf(fmaxf(v.x,v.y), fmaxf(v.z,v.w)));
  }
  mx = wredmax(mx);
  float e1=0.0f;
  #pragma unroll
  for (int k=0;k<8;k++){
    float4 v = vals[k];
    e1 += __expf(v.x-mx)+__expf(v.y-mx)+__expf(v.z-mx)+__expf(v.w-mx);
  }
  e1 = wredsum(e1);
  const float l = mx + __logf(e1);
  uint2* rowh2 = (uint2*)row;
  float y2 = 0.0f;
  #pragma unroll
  for (int k=0;k<8;k++){
    float4 v = vals[k];
    unsigned short h0 = f2h(__expf((v.x-l)*invrho));
    unsigned short h1 = f2h(__expf((v.y-l)*invrho));
    unsigned short h2 = f2h(__expf((v.z-l)*invrho));
    unsigned short h3 = f2h(__expf((v.w-l)*invrho));
    y2 += h2f(h0)+h2f(h1)+h2f(h2)+h2f(h3);
    uint2 pk;
    pk.x = (unsigned)h0 | ((unsigned)h1<<16);
    pk.y = (unsigned)h2 | ((unsigned)h3<<16);
    rowh2[lane + 64*k] = pk;
  }
  y2 = wredsum(y2);
  if (lane==0) y0[b*M_+m] = y2;
}

// ===== persistent Sinkhorn: init + it0-col + 4x(vupd+row+col) + final vupd =====
// Spill-free redesign (R3 spilled: sv[32] cache pushed live state past 128 VGPRs
// -> 458 MB scratch writes).  Now: keep raw su[4] uint4 (16 regs), unpack TWICE
// (h2f is 1 VALU op); u lives in LDS ush[4][16].  Peak live ~75 VGPRs.
#define VIDX(j) ((j) + (((j)>>5)<<2))    // +4 floats per 32: 16B-aligned pad

__device__ __forceinline__ void batch_barrier(unsigned int* ctr){
  __syncthreads();
  if (threadIdx.x==0){
    __hip_atomic_fetch_add(ctr, 1u, __ATOMIC_RELEASE, __HIP_MEMORY_SCOPE_AGENT);
    while (__hip_atomic_load(ctr, __ATOMIC_ACQUIRE, __HIP_MEMORY_SCOPE_AGENT) < NCH)
      __builtin_amdgcn_s_sleep(2);
  }
  __syncthreads();
}

__global__ __launch_bounds__(256, 2) void sinkhorn_kernel(const float* __restrict__ S,
                                                          const float* __restrict__ y0,
                                                          float* __restrict__ u,
                                                          float* __restrict__ v,
                                                          float* __restrict__ g,
                                                          float* __restrict__ wbuf,
                                                          unsigned int* __restrict__ bar)
{
  __shared__ float vloc[2304];        // 2048 + pad
  __shared__ float wsh[4][2048];
  __shared__ float ush[4][16];
  __shared__ float redsh[4];
  const int b = blockIdx.y, chunk = blockIdx.x;
  const int t = threadIdx.x, wid = t>>6, lane = t&63;
  const int i0 = chunk*64;

  // ---- init: g0 = 1/sum(y0[b]); u0 for my rows (LDS); v = 1 ----
  float s0 = 0.0f;
  for (int i=t;i<N_;i+=256) s0 += y0[b*M_+i];
  s0 = wredsum(s0);
  if (lane==0) redsh[wid]=s0;
  __syncthreads();
  float gcur = 1.0f / fmaxf(redsh[0]+redsh[1]+redsh[2]+redsh[3], EPSF);
  if (lane < 16){
    float ys = y0[b*M_ + i0 + wid*16 + lane];
    ush[wid][lane] = fminf(AVAL / fmaxf(gcur*ys, EPSF), 1.0f);
  }
  for (int i=t;i<N_;i+=256) vloc[VIDX(i)] = 1.0f;
  __syncthreads();

  float acc[32];

  // ---- it0: col only (u0 is the first row update) -> w slice 0 ----
  #pragma unroll
  for (int k=0;k<32;k++) acc[k]=0.0f;
  for (int r=0;r<16;r++){
    const uint4* rowh = (const uint4*)(S + (size_t)(b*M_ + i0 + wid*16 + r)*N_);
    uint4 su[4];
    #pragma unroll
    for (int k=0;k<4;k++) su[k] = rowh[lane + 64*k];
    const float un = ush[wid][r];
    #pragma unroll
    for (int k=0;k<4;k++){
      acc[k*8+0] += un*h2f((unsigned short)(su[k].x&0xffff));
      acc[k*8+1] += un*h2f((unsigned short)(su[k].x>>16));
      acc[k*8+2] += un*h2f((unsigned short)(su[k].y&0xffff));
      acc[k*8+3] += un*h2f((unsigned short)(su[k].y>>16));
      acc[k*8+4] += un*h2f((unsigned short)(su[k].z&0xffff));
      acc[k*8+5] += un*h2f((unsigned short)(su[k].z>>16));
      acc[k*8+6] += un*h2f((unsigned short)(su[k].w&0xffff));
      acc[k*8+7] += un*h2f((unsigned short)(su[k].w>>16));
    }
  }
  {
    #pragma unroll
    for (int k=0;k<4;k++)
      #pragma unroll
      for (int e=0;e<8;e++)
        wsh[wid][(lane+64*k)*8+e] = acc[k*8+e];
    __syncthreads();
    float* w0 = wbuf + b*N_;
    #pragma unroll
    for (int e=0;e<8;e++){
      int j = t*8+e;
      atomicAdd(&w0[j], wsh[0][j]+wsh[1][j]+wsh[2][j]+wsh[3][j]);
    }
  }
  batch_barrier(&bar[b*8 + 0]);

  // ---- it = 1..4: local vupd (redundant, deterministic) + fused row/col ----
  for (int it=1; it<=4; ++it){
    const float* wprev = wbuf + (size_t)(it-1)*B_*N_ + b*N_;
    float part = 0.0f;
    for (int i=t;i<N_;i+=256){
      float wj = __hip_atomic_load(&wprev[i], __ATOMIC_RELAXED, __HIP_MEMORY_SCOPE_AGENT);
      float vj = vloc[VIDX(i)];
      float c  = fminf(AVAL / fmaxf(gcur*vj*wj, EPSF), 1.0f);
      vj *= c;
      vloc[VIDX(i)] = vj;
      part += wj*vj;
    }
    part = wredsum(part);
    if (lane==0) redsh[wid]=part;
    __syncthreads();    // also publishes vloc updates to all warps
    {
      float tot = gcur*(redsh[0]+redsh[1]+redsh[2]+redsh[3]);
      gcur = gcur / fmaxf(tot, EPSF);
    }
    // fused row update + col accumulation (one K̂ read, two unpacks)
    #pragma unroll
    for (int k=0;k<32;k++) acc[k]=0.0f;
    for (int r=0;r<16;r++){
      const uint4* rowh = (const uint4*)(S + (size_t)(b*M_ + i0 + wid*16 + r)*N_);
      uint4 su[4];
      #pragma unroll
      for (int k=0;k<4;k++) su[k] = rowh[lane + 64*k];
      float dot = 0.0f;
      #pragma unroll
      for (int k=0;k<4;k++){
        const int pb = VIDX((lane+64*k)*8);
        float4 v0 = *(const float4*)&vloc[pb];
        float4 v1 = *(const float4*)&vloc[pb+4];
        dot += h2f((unsigned short)(su[k].x&0xffff))*v0.x
             + h2f((unsigned short)(su[k].x>>16))   *v0.y
             + h2f((unsigned short)(su[k].y&0xffff))*v0.z
             + h2f((unsigned short)(su[k].y>>16))   *v0.w
             + h2f((unsigned short)(su[k].z&0xffff))*v1.x
             + h2f((unsigned short)(su[k].z>>16))   *v1.y
             + h2f((unsigned short)(su[k].w&0xffff))*v1.z
             + h2f((unsigned short)(su[k].w>>16))   *v1.w;
      }
      dot = wredsum(dot);
      float ui = ush[wid][r];
      float rs = gcur*ui*dot;
      float un = ui * fminf(AVAL / fmaxf(rs, EPSF), 1.0f);
      if (lane==0) ush[wid][r] = un;
      #pragma unroll
      for (int k=0;k<4;k++){
        acc[k*8+0] += un*h2f((unsigned short)(su[k].x&0xffff));
        acc[k*8+1] += un*h2f((unsigned short)(su[k].x>>16));
        acc[k*8+2] += un*h2f((unsigned short)(su[k].y&0xffff));
        acc[k*8+3] += un*h2f((unsigned short)(su[k].y>>16));
        acc[k*8+4] += un*h2f((unsigned short)(su[k].z&0xffff));
        acc[k*8+5] += un*h2f((unsigned short)(su[k].z>>16));
        acc[k*8+6] += un*h2f((unsigned short)(su[k].w&0xffff));
        acc[k*8+7] += un*h2f((unsigned short)(su[k].w>>16));
      }
    }
    __syncthreads();   // wsh reuse safe (prev combine finished before barrier)
    #pragma unroll
    for (int k=0;k<4;k++)
      #pragma unroll
      for (int e=0;e<8;e++)
        wsh[wid][(lane+64*k)*8+e] = acc[k*8+e];
    __syncthreads();
    float* wcur = wbuf + (size_t)it*B_*N_ + b*N_;
    #pragma unroll
    for (int e=0;e<8;e++){
      int j = t*8+e;
      atomicAdd(&wcur[j], wsh[0][j]+wsh[1][j]+wsh[2][j]+wsh[3][j]);
    }
    batch_barrier(&bar[b*8 + it]);
  }

  // ---- final vupd (w slice 4) -> v5, g5; write back u, v, g ----
  {
    const float* wprev = wbuf + (size_t)4*B_*N_ + b*N_;
    float part = 0.0f;
    for (int i=t;i<N_;i+=256){
      float wj = __hip_atomic_load(&wprev[i], __ATOMIC_RELAXED, __HIP_MEMORY_SCOPE_AGENT);
      float vj = vloc[VIDX(i)];
      float c  = fminf(AVAL / fmaxf(gcur*vj*wj, EPSF), 1.0f);
      vj *= c;
      vloc[VIDX(i)] = vj;
      part += wj*vj;
    }
    part = wredsum(part);
    if (lane==0) redsh[wid]=part;
    __syncthreads();
    float tot = gcur*(redsh[0]+redsh[1]+redsh[2]+redsh[3]);
    gcur = gcur / fmaxf(tot, EPSF);
  }
  if (lane < 16)
    u[b*M_ + i0 + wid*16 + lane] = ush[wid][lane];
  if (chunk==0){
    for (int i=t;i<N_;i+=256) v[b*N_+i] = vloc[VIDX(i)];
    if (t==0) g[b] = gcur;
  }
}

// ---- final: matches fp32 overwrite rows in place; fused rowsum + matches@t^T ----
__global__ __launch_bounds__(256) void final_kernel(float* __restrict__ S,
                                                    const float* __restrict__ u,
                                                    const float* __restrict__ v,
                                                    const float* __restrict__ g,
                                                    const float* __restrict__ tgt,
                                                    float* __restrict__ rowsum,
                                                    float* __restrict__ wref)
{
  const int b = blockIdx.y;
  const int m = blockIdx.x*4 + (threadIdx.x>>6);
  const int lane = threadIdx.x & 63;
  const float gu = g[b]*u[b*M_+m];
  float* row = S + (size_t)(b*M_ + m)*N_;
  const uint4* rowh = (const uint4*)row;
  uint4 su[4];
  #pragma unroll
  for (int k=0;k<4;k++) su[k] = rowh[lane + 64*k];
  __builtin_amdgcn_s_waitcnt(0);
  float4* rowf = (float4*)row;
  const float4* vp = (const float4*)(v + (size_t)b*N_);
  const float4* t0 = (const float4*)(tgt + ((size_t)b*3+0)*N_);
  const float4* t1 = (const float4*)(tgt + ((size_t)b*3+1)*N_);
  const float4* t2 = (const float4*)(tgt + ((size_t)b*3+2)*N_);
  float rs=0.0f, a0=0.0f, a1=0.0f, a2=0.0f;
  #pragma unroll
  for (int k=0;k<4;k++){
    float s[8] = {h2f((unsigned short)(su[k].x&0xffff)), h2f((unsigned short)(su[k].x>>16)),
                  h2f((unsigned short)(su[k].y&0xffff)), h2f((unsigned short)(su[k].y>>16)),
                  h2f((unsigned short)(su[k].z&0xffff)), h2f((unsigned short)(su[k].z>>16)),
                  h2f((unsigned short)(su[k].w&0xffff)), h2f((unsigned short)(su[k].w>>16))};
    int i2 = (lane+64*k)*2;
    #pragma unroll
    for (int h=0;h<2;h++){
      float4 v4 = vp[i2+h];
      float4 q0 = t0[i2+h], q1 = t1[i2+h], q2 = t2[i2+h];
      float m0 = gu*s[h*4+0]*v4.x;
      float m1 = gu*s[h*4+1]*v4.y;
      float m2 = gu*s[h*4+2]*v4.z;
      float m3 = gu*s[h*4+3]*v4.w;
      rs += m0+m1+m2+m3;
      a0 += m0*q0.x + m1*q0.y + m2*q0.z + m3*q0.w;
      a1 += m0*q1.x + m1*q1.y + m2*q1.z + m3*q1.w;
      a2 += m0*q2.x + m1*q2.y + m2*q2.z + m3*q2.w;
      rowf[i2+h] = make_float4(m0,m1,m2,m3);
    }
  }
  rs = wredsum(rs); a0=wredsum(a0); a1=wredsum(a1); a2=wredsum(a2);
  if (lane==0){
    rowsum[b*M_+m] = rs;
    float inv = 1.0f/(rs+1e-6f);
    size_t o = ((size_t)b*M_+m)*3;
    wref[o]=a0*inv; wref[o+1]=a1*inv; wref[o+2]=a2*inv;
  }
}

// ---------------- 3x3 Kabsch via Jacobi on cov^T cov (verified R1) ----------------
__device__ __forceinline__ void mat3_svd_rot(const float cov[3][3], float R[3][3])
{
  float mx = 1e-30f;
  for (int p=0;p<3;p++) for (int q=0;q<3;q++) mx = fmaxf(mx, fabsf(cov[p][q]));
  const float inv = 1.0f/mx;
  float Cm[3][3];
  for (int p=0;p<3;p++) for (int q=0;q<3;q++) Cm[p][q]=cov[p][q]*inv;
  float G[3][3];
  for (int p=0;p<3;p++)
    for (int q=0;q<3;q++)
      G[p][q] = Cm[0][p]*Cm[0][q] + Cm[1][p]*Cm[1][q] + Cm[2][p]*Cm[2][q];
  float V[3][3] = {{1,0,0},{0,1,0},{0,0,1}};
  const int PP[3]={0,0,1}, QQ[3]={1,2,2};
  for (int sweep=0;sweep<12;sweep++){
    for (int r=0;r<3;r++){
      int p=PP[r], q=QQ[r];
      float apq = G[p][q];
      if (fabsf(apq) < 1e-20f) continue;
      float tau = (G[q][q]-G[p][p])/(2.0f*apq);
      float tt  = (tau>=0.0f?1.0f:-1.0f)/(fabsf(tau)+sqrtf(1.0f+tau*tau));
      float cc  = 1.0f/sqrtf(1.0f+tt*tt);
      float ss  = tt*cc;
      for (int k=0;k<3;k++){ float gkp=G[k][p], gkq=G[k][q]; G[k][p]=cc*gkp-ss*gkq; G[k][q]=ss*gkp+cc*gkq; }
      for (int k=0;k<3;k++){ float gpk=G[p][k], gqk=G[q][k]; G[p][k]=cc*gpk-ss*gqk; G[q][k]=ss*gpk+cc*gqk; }
      for (int k=0;k<3;k++){ float vkp=V[k][p], vkq=V[k][q]; V[k][p]=cc*vkp-ss*vkq; V[k][q]=ss*vkp+cc*vkq; }
    }
  }
  float ev[3]={G[0][0],G[1][1],G[2][2]};
  int i0=0,i1=1,i2=2,tmp;
  if (ev[i0]<ev[i1]){tmp=i0;i0=i1;i1=tmp;}
  if (ev[i0]<ev[i2]){tmp=i0;i0=i2;i2=tmp;}
  if (ev[i1]<ev[i2]){tmp=i1;i1=i2;i2=tmp;}
  const int idx[3]={i0,i1,i2};
  float Vs[3][3];
  for (int k=0;k<3;k++) for (int i=0;i<3;i++) Vs[i][k]=V[i][idx[k]];
  float U[3][3]; float nrm[3];
  for (int k=0;k<3;k++){
    float ux = Cm[0][0]*Vs[0][k]+Cm[0][1]*Vs[1][k]+Cm[0][2]*Vs[2][k];
    float uy = Cm[1][0]*Vs[0][k]+Cm[1][1]*Vs[1][k]+Cm[1][2]*Vs[2][k];
    float uz = Cm[2][0]*Vs[0][k]+Cm[2][1]*Vs[1][k]+Cm[2][2]*Vs[2][k];
    float n = sqrtf(ux*ux+uy*uy+uz*uz);
    nrm[k]=n;
    float in = (n>1e-20f)?1.0f/n:0.0f;
    U[0][k]=ux*in; U[1][k]=uy*in; U[2][k]=uz*in;
  }
  if (nrm[2] < 1e-6f*fmaxf(nrm[0],1e-20f)){
    U[0][2]=U[1][0]*U[2][1]-U[2][0]*U[1][1];
    U[1][2]=U[2][0]*U[0][1]-U[0][0]*U[2][1];
    U[2][2]=U[0][0]*U[1][1]-U[1][0]*U[0][1];
  }
  float detC = Cm[0][0]*(Cm[1][1]*Cm[2][2]-Cm[1][2]*Cm[2][1])
             - Cm[0][1]*(Cm[1][0]*Cm[2][2]-Cm[1][2]*Cm[2][0])
             + Cm[0][2]*(Cm[1][0]*Cm[2][1]-Cm[1][1]*Cm[2][0]);
  float d2 = (detC>0.0f)?1.0f:-1.0f;
  for (int p=0;p<3;p++)
    for (int q=0;q<3;q++)
      R[p][q] = Vs[p][0]*U[q][0] + Vs[p][1]*U[q][1] + d2*Vs[p][2]*U[q][2];
}

__global__ __launch_bounds__(256) void rigid_kernel(const float* __restrict__ src,
                                                    const float* __restrict__ wref,
                                                    const float* __restrict__ rowsum,
                                                    float* __restrict__ out)
{
  const int b = blockIdx.x; const int t = threadIdx.x;
  float acc[16];
  #pragma unroll
  for (int k=0;k<16;k++) acc[k]=0.0f;
  for (int i=t;i<M_;i+=256){
    float wgt = rowsum[b*M_+i];
    float ax = src[((size_t)b*3+0)*M_+i];
    float ay = src[((size_t)b*3+1)*M_+i];
    float az = src[((size_t)b*3+2)*M_+i];
    const float* wr = wref + ((size_t)b*M_+i)*3;
    float bx=wr[0], by=wr[1], bz=wr[2];
    acc[0]+=wgt;
    acc[1]+=wgt*ax; acc[2]+=wgt*ay; acc[3]+=wgt*az;
    acc[4]+=wgt*bx; acc[5]+=wgt*by; acc[6]+=wgt*bz;
    acc[7] +=wgt*ax*bx; acc[8] +=wgt*ax*by; acc[9] +=wgt*ax*bz;
    acc[10]+=wgt*ay*bx; acc[11]+=wgt*ay*by; acc[12]+=wgt*ay*bz;
    acc[13]+=wgt*az*bx; acc[14]+=wgt*az*by; acc[15]+=wgt*az*bz;
  }
  __shared__ float red[4][16];
  const int wid = t>>6, lane = t&63;
  #pragma unroll
  for (int k=0;k<16;k++){
    float v = acc[k];
    #pragma unroll
    for (int off=32; off; off>>=1) v += __shfl_xor(v, off);
    if (lane==0) red[wid][k]=v;
  }
  __syncthreads();
  if (t==0){
    float s[16];
    #pragma unroll
    for (int k=0;k<16;k++) s[k]=red[0][k]+red[1][k]+red[2][k]+red[3][k];
    float wsum = s[0];
    float denom = wsum + 1e-6f;
    float ca[3]={s[1]/denom, s[2]/denom, s[3]/denom};
    float cb[3]={s[4]/denom, s[5]/denom, s[6]/denom};
    float sw = wsum/denom;
    float cov[3][3];
    for (int p=0;p<3;p++)
      for (int q=0;q<3;q++)
        cov[p][q] = s[7+p*3+q]/denom + (sw-2.0f)*ca[p]*cb[q];
    float R[3][3];
    mat3_svd_rot(cov, R);
    float tr[3];
    for (int p=0;p<3;p++)
      tr[p] = -(R[p][0]*ca[0]+R[p][1]*ca[1]+R[p][2]*ca[2]) + cb[p];
    for (int p=0;p<3;p++)
      for (int q=0;q<3;q++)
        out[b*9 + p*3 + q] = R[p][q];
    for (int p=0;p<3;p++)
      out[144 + b*3 + p] = tr[p];
  }
}

extern "C" void kernel_launch(void* const* d_in, const int* in_sizes, int n_in,
                              void* d_out, int out_size, void* d_ws, size_t ws_size,
                              hipStream_t stream)
{
  const float* se  = (const float*)d_in[0];
  const float* te  = (const float*)d_in[1];
  const float* src = (const float*)d_in[2];
  const float* tgt = (const float*)d_in[3];
  const float* rho = (const float*)d_in[4];
  float* out = (float*)d_out;
  float* S   = out + 192;                 // matches region doubles as S / K̂ scratch
  float* ws  = (float*)d_ws;

  // ws layout (floats)
  float*        y0   = ws;                         // 32768 (also final rowsum)
  float*        u    = ws + 32768;                 // 32768
  float*        v    = ws + 65536;                 // 32768
  float*        g    = ws + 98304;                 // 16
  float*        wref = ws + 98320;                 // 98304 -> ends 196624
  float*        wbuf = ws + 196624;                // 5*32768 = 163840 -> ends 360464
  unsigned int* bar  = (unsigned int*)(ws + 360464); // 128 u32 -> ends 360592
  const int     ZCNT = 163840 + 128;               // wbuf + bar zero region
  float*        zb   = wbuf;

  // split-bf16 operand planes
  const size_t PLANE_G     = (size_t)16*32*2048;          // granules per plane
  const size_t PLANE_BYTES = PLANE_G*16;                  // 16.78 MB
  const size_t PLANE_OFF   = (size_t)360592*4;            // byte 1442368, 16B-aligned
  const size_t need        = PLANE_OFF + 4*PLANE_BYTES;   // ~68.6 MB

  if (ws_size >= need){
    uint4* Ah = (uint4*)((char*)d_ws + PLANE_OFF);
    uint4* Al = Ah + PLANE_G;
    uint4* Bh = Al + PLANE_G;
    uint4* Bl = Bh + PLANE_G;
    convert_kernel<<<dim3(8,32,32),256,0,stream>>>(se,te,Ah,Al,Bh,Bl,zb,ZCNT);
    gemm_fast     <<<dim3(16,16,16),256,0,stream>>>(Ah,Al,Bh,Bl,S);
  } else {
    zero_kernel   <<<dim3((ZCNT+255)/256),256,0,stream>>>(zb,ZCNT);
    gemm_kernel   <<<dim3(16,16,16),256,0,stream>>>(se,te,S);
  }
  stats_kernel   <<<dim3(512,16),  256,0,stream>>>(S,rho,y0);
  sinkhorn_kernel<<<dim3(NCH,16),  256,0,stream>>>(S,y0,u,v,g,wbuf,bar);
  final_kernel   <<<dim3(512,16),  256,0,stream>>>(S,u,v,g,tgt,y0,wref);
  rigid_kernel   <<<dim3(16),      256,0,stream>>>(src,wref,y0,out);
}